// Round 18
// baseline (70.976 us; speedup 1.0000x reference)
//
#include <hip/hip_runtime.h>
#include <hip/hip_bf16.h>
#include <stdint.h>

typedef __bf16 bf16;
typedef __attribute__((ext_vector_type(8))) __bf16 bf16x8;
typedef __attribute__((ext_vector_type(2))) __bf16 bf16x2;
typedef __attribute__((ext_vector_type(4))) float f32x4;
typedef __attribute__((ext_vector_type(4))) unsigned int u32x4;

#define GLOAD16(gsrc, ldst)                                              \
  __builtin_amdgcn_global_load_lds(                                      \
      (const __attribute__((address_space(1))) unsigned int*)(gsrc),     \
      (__attribute__((address_space(3))) unsigned int*)(ldst), 16, 0, 0)

static constexpr int T_LEN = 4096;
static constexpr int WIN = 16;

__device__ __forceinline__ bf16x8 cvt8(float4 a, float4 b) {
  bf16x8 o;
  o[0] = (bf16)a.x; o[1] = (bf16)a.y; o[2] = (bf16)a.z; o[3] = (bf16)a.w;
  o[4] = (bf16)b.x; o[5] = (bf16)b.y; o[6] = (bf16)b.z; o[7] = (bf16)b.w;
  return o;
}

// ---- fused casts: blocks 0..2047 -> x, 2048..2559 -> weights ----
__global__ __launch_bounds__(256) void prep_kernel(const float* __restrict__ x,
                                                   const float* __restrict__ wq,
                                                   const float* __restrict__ wk,
                                                   const float* __restrict__ wv,
                                                   const float* __restrict__ wp,
                                                   bf16* __restrict__ xb,
                                                   bf16* __restrict__ wqkv,
                                                   bf16* __restrict__ wpb) {
  int bid = blockIdx.x;
  if (bid < 2048) {
    int i = bid * 256 + threadIdx.x;
    const float4* s4 = (const float4*)x + (size_t)i * 2;
    ((bf16x8*)xb)[i] = cvt8(s4[0], s4[1]);
  } else {
    int i = (bid - 2048) * 256 + threadIdx.x;
    int which = i >> 15;
    int j = i & 32767;
    const float* src = (which == 0) ? wq : (which == 1) ? wk : (which == 2) ? wv : wp;
    bf16* dst = (which < 3) ? (wqkv + (size_t)which * 512 * 512) : wpb;
    const float4* s4 = (const float4*)src + (size_t)j * 2;
    ((bf16x8*)dst)[j] = cvt8(s4[0], s4[1]);
  }
}

// ---- QKV GEMM: single-buffer 2-barrier loop, 128x64 tiles -> 1536 blocks ----
__global__ __launch_bounds__(256) void gemm_qkv_kernel(const bf16* __restrict__ Ab,
                                                       const bf16* __restrict__ Bw,
                                                       bf16* __restrict__ Cb) {
  constexpr int K = 512, BK = 64, NIT = K / BK;  // 8
  __shared__ __align__(16) bf16 As[8192];  // 128 rows x 64
  __shared__ __align__(16) bf16 Bs[4096];  // 64 rows x 64
  const int tid = threadIdx.x;
  const int l = tid & 63;
  const int w = tid >> 6;
  const int g = l >> 4;
  const int c = l & 15;
  int bid = blockIdx.x;
  bid = (bid & 7) * 192 + (bid >> 3);  // XCD swizzle (1536 = 8*192)
  const int m0 = (bid / 24) * 128;     // 64 M-tiles
  const int n0 = (bid % 24) * 64;      // 24 N-tiles

  const int wm = (w >> 1) * 64;
  const int wn = (w & 1) * 32;
  const int cx = c & 7;

  const f32x4 zero = {0.f, 0.f, 0.f, 0.f};
  f32x4 acc[4][2];
#pragma unroll
  for (int i = 0; i < 4; ++i)
#pragma unroll
    for (int j = 0; j < 2; ++j) acc[i][j] = zero;

#pragma unroll 1
  for (int t = 0; t < NIT; ++t) {
    const int k0 = t * BK;
#pragma unroll
    for (int i = 0; i < 4; ++i) {  // A: 128 rows x 8 chunks = 1024 slots
      int s = tid + i * 256;
      int row = s >> 3;
      int j = s & 7;
      GLOAD16(Ab + (size_t)(m0 + row) * 512 + k0 + ((j ^ (row & 7)) << 3),
              &As[s * 8]);
    }
#pragma unroll
    for (int i = 0; i < 2; ++i) {  // B: 64 rows x 8 chunks = 512 slots
      int s = tid + i * 256;
      int row = s >> 3;
      int j = s & 7;
      GLOAD16(Bw + (size_t)(n0 + row) * 512 + k0 + ((j ^ (row & 7)) << 3),
              &Bs[s * 8]);
    }
    __syncthreads();
#pragma unroll
    for (int kk = 0; kk < 2; ++kk) {
      const int joff = ((kk * 4 + g) ^ cx) << 3;
      bf16x8 af[4], bfr[2];
#pragma unroll
      for (int mi = 0; mi < 4; ++mi)
        af[mi] = *(const bf16x8*)&As[(wm + mi * 16 + c) * 64 + joff];
#pragma unroll
      for (int ni = 0; ni < 2; ++ni)
        bfr[ni] = *(const bf16x8*)&Bs[(wn + ni * 16 + c) * 64 + joff];
#pragma unroll
      for (int mi = 0; mi < 4; ++mi)
#pragma unroll
        for (int ni = 0; ni < 2; ++ni)
          acc[mi][ni] = __builtin_amdgcn_mfma_f32_16x16x32_bf16(af[mi], bfr[ni], acc[mi][ni], 0, 0, 0);
    }
    __syncthreads();
  }

  // ---- C epilogue: wave-private LDS bounce (64x32, 4KB/wave in As) ----
  bf16* Cw = &As[w * 2048];
  const int r0 = (l >> 4) * 4;
#pragma unroll
  for (int mi = 0; mi < 4; ++mi)
#pragma unroll
    for (int ni = 0; ni < 2; ++ni)
#pragma unroll
      for (int r = 0; r < 4; ++r)
        Cw[(mi * 16 + r0 + r) * 32 + ni * 16 + c] = (bf16)acc[mi][ni][r];
#pragma unroll
  for (int i = 0; i < 4; ++i) {
    int row = (l >> 2) + 16 * i;
    bf16x8 v = *(const bf16x8*)&Cw[row * 32 + (l & 3) * 8];
    *(bf16x8*)(Cb + (size_t)(m0 + wm + row) * 1536 + n0 + wn + (l & 3) * 8) = v;
  }
}

// ---- FUSED attn + proj + residual + LN, BM=16, grid 512 (2 blocks/CU) ----
// Wave = one head per pass (4 waves, 2 passes). Per head: K[48][72], Vt[64][56]
// (pads 48..55 zeroed; V^T scatter rotated -> conflict-free). Proj: A from LDS
// aoutL[16][520], B direct from global (Wp L2-resident) -> barrier-free loop.
__global__ __launch_bounds__(256) void attn_proj_ln_kernel(
    const bf16* __restrict__ qkv, const bf16* __restrict__ Bw,
    const float* __restrict__ X, const float* __restrict__ gamma,
    const float* __restrict__ beta, float* __restrict__ out) {
  __shared__ __align__(16) bf16 POOL[40320];  // 80,640 B -> 2 blocks/CU
  bf16* KV = POOL;                      // 4 slots x (K 3456 + Vt 3584) = 28160
  bf16* Pp = POOL + 28160;              // 4 waves x 896
  bf16* aoutL = POOL + 31744;           // [16][520] = 8320
  float* rsum = (float*)(POOL + 40064); // [16][4]
  float* rsq  = (float*)(POOL + 40192); // [16][4]

  const int tid = threadIdx.x;
  const int w = tid >> 6;
  const int l = tid & 63;
  const int g = l >> 4;
  const int c = l & 15;
  int bid = blockIdx.x;
  bid = (bid & 7) * 64 + (bid >> 3);  // XCD swizzle: 512 = 8*64
  const int m0 = bid * 16;
  const int b = m0 >> 12;
  const int tloc0 = m0 & (T_LEN - 1);
  const int base = b * T_LEN;

  const f32x4 zero = {0.f, 0.f, 0.f, 0.f};
  const u32x4 zu = {0u, 0u, 0u, 0u};
  const float scale = 0.125f;

  // ---- zero Vt pad cols 48..55 (4 slots x 64 rows; read where P=0) ----
  {
    int hl = tid >> 6;
    int row = tid & 63;
    *(uint4*)&KV[hl * 7040 + 3456 + row * 56 + 48] = make_uint4(0u, 0u, 0u, 0u);
  }

  // ================= attention phase (2 passes x 4 heads) =================
#pragma unroll 1
  for (int pass = 0; pass < 2; ++pass) {
    if (pass) __syncthreads();  // prior pass's K/V reads done before restage
    // stage: 1536 tasks = 4 heads x 48 pos x 8 chunks
#pragma unroll
    for (int i = 0; i < 6; ++i) {
      int task = tid + i * 256;
      int hl = task / 384;
      int rem = task - hl * 384;
      int pp = rem >> 3;
      int c8 = (rem & 7) * 8;
      int h = pass * 4 + hl;
      int pg = base + min(max(tloc0 - WIN + pp, 0), T_LEN - 1);
      const bf16* kr = qkv + (size_t)pg * 1536 + 512 + h * 64 + c8;
      const bf16* vr = qkv + (size_t)pg * 1536 + 1024 + h * 64 + c8;
      *(bf16x8*)&KV[hl * 7040 + pp * 72 + c8] = *(const bf16x8*)kr;
      bf16x8 vv = *(const bf16x8*)vr;
      bf16* vt = &KV[hl * 7040 + 3456];
      int rot = (c8 >> 3) & 7;
#pragma unroll
      for (int e = 0; e < 8; ++e) {
        int er = (e + rot) & 7;  // rotated scatter -> conflict-free banks
        vt[(c8 + er) * 56 + pp] = vv[er];
      }
    }
    __syncthreads();

    const int h = pass * 4 + w;  // wave = head
    bf16* Kl = &KV[w * 7040];
    bf16* Vt = &KV[w * 7040 + 3456];

    // Q fragments (global): k-map (g,e) -> d = 32*kh + 8g + e
    const bf16* qrow = qkv + (size_t)(base + tloc0 + c) * 1536 + h * 64;
    bf16x8 qf0 = *(const bf16x8*)(qrow + g * 8);
    bf16x8 qf1 = *(const bf16x8*)(qrow + 32 + g * 8);

    // S^T = K @ Q^T (48 w x 16 q)
    f32x4 st[3];
#pragma unroll
    for (int wt = 0; wt < 3; ++wt) {
      int rk = 16 * wt + c;
      bf16x8 ka0 = *(const bf16x8*)&Kl[rk * 72 + g * 8];
      bf16x8 ka1 = *(const bf16x8*)&Kl[rk * 72 + 32 + g * 8];
      f32x4 t = __builtin_amdgcn_mfma_f32_16x16x32_bf16(ka0, qf0, zero, 0, 0, 0);
      st[wt] = __builtin_amdgcn_mfma_f32_16x16x32_bf16(ka1, qf1, t, 0, 0, 0);
    }

    // masked exp + row-sum (q=c; w-off = 16wt+4g+r; pos = tloc0-16+w)
    float pv[3][4];
    float lsum = 0.f;
#pragma unroll
    for (int wt = 0; wt < 3; ++wt)
#pragma unroll
      for (int r = 0; r < 4; ++r) {
        int ww = 16 * wt + 4 * g + r;
        int pos = tloc0 - WIN + ww;
        bool valid = (ww >= c) && (ww <= c + 32) && (pos >= 0) && (pos < T_LEN);
        float e = __expf(st[wt][r] * scale);
        pv[wt][r] = valid ? e : 0.f;
        lsum += pv[wt][r];
      }
    lsum += __shfl_xor(lsum, 16);
    lsum += __shfl_xor(lsum, 32);
    float inv = 1.f / lsum;

    // normalized P (stride 56) in per-wave region
    bf16* P = &Pp[w * 896];
#pragma unroll
    for (int wt = 0; wt < 3; ++wt) {
      bf16x2 p01, p23;
      p01[0] = (bf16)(pv[wt][0] * inv);
      p01[1] = (bf16)(pv[wt][1] * inv);
      p23[0] = (bf16)(pv[wt][2] * inv);
      p23[1] = (bf16)(pv[wt][3] * inv);
      *(bf16x2*)&P[c * 56 + 16 * wt + 4 * g]     = p01;
      *(bf16x2*)&P[c * 56 + 16 * wt + 4 * g + 2] = p23;
    }

    bf16x8 pa0 = *(const bf16x8*)&P[c * 56 + 8 * g];
    int g1 = (g < 2) ? g : 1;
    bf16x8 pa1 = *(const bf16x8*)&P[c * 56 + 32 + 8 * g1];
    if (g >= 2) pa1 = __builtin_bit_cast(bf16x8, zu);  // w>=48 -> P=0

    const int off0 = 8 * g;
    const int off1 = (g < 2) ? 32 + 8 * g : 48;  // 48 = zero pad
    f32x4 acc[4] = {zero, zero, zero, zero};
#pragma unroll
    for (int dt = 0; dt < 4; ++dt) {
      bf16x8 v0 = *(const bf16x8*)&Vt[(16 * dt + c) * 56 + off0];
      bf16x8 v1 = *(const bf16x8*)&Vt[(16 * dt + c) * 56 + off1];
      acc[dt] = __builtin_amdgcn_mfma_f32_16x16x32_bf16(pa0, v0, acc[dt], 0, 0, 0);
      acc[dt] = __builtin_amdgcn_mfma_f32_16x16x32_bf16(pa1, v1, acc[dt], 0, 0, 0);
    }

    // aoutL[16][520]: row = 4g+r, col = h*64 + 16dt + c
#pragma unroll
    for (int dt = 0; dt < 4; ++dt)
#pragma unroll
      for (int r = 0; r < 4; ++r)
        aoutL[(4 * g + r) * 520 + h * 64 + 16 * dt + c] = (bf16)acc[dt][r];
  }
  __syncthreads();  // aoutL complete

  // ======== proj phase: barrier-free; A from LDS, B from global (L2) ========
  const int wcol = w * 128;
  f32x4 acc2[8];
#pragma unroll
  for (int n = 0; n < 8; ++n) acc2[n] = zero;

#pragma unroll
  for (int kt = 0; kt < 16; ++kt) {  // K = 16 x 32
    bf16x8 af = *(const bf16x8*)&aoutL[c * 520 + kt * 32 + g * 8];
#pragma unroll
    for (int n = 0; n < 8; ++n) {
      bf16x8 bfv = *(const bf16x8*)(Bw + (size_t)(wcol + n * 16 + c) * 512 +
                                    kt * 32 + g * 8);
      acc2[n] = __builtin_amdgcn_mfma_f32_16x16x32_bf16(af, bfv, acc2[n], 0, 0, 0);
    }
  }

  // residual + LN partials (rows 4g+r, cols wcol + n*16 + c)
  float ps[4], ps2[4];
#pragma unroll
  for (int r = 0; r < 4; ++r) {
    int row = m0 + 4 * g + r;
    float s = 0.f, s2 = 0.f;
#pragma unroll
    for (int n = 0; n < 8; ++n) {
      float y = acc2[n][r] + X[(size_t)row * 512 + wcol + n * 16 + c];
      acc2[n][r] = y;
      s += y;
      s2 += y * y;
    }
    ps[r] = s;
    ps2[r] = s2;
  }
#pragma unroll
  for (int r = 0; r < 4; ++r) {
    float s = ps[r], s2 = ps2[r];
    s += __shfl_xor(s, 1);  s2 += __shfl_xor(s2, 1);
    s += __shfl_xor(s, 2);  s2 += __shfl_xor(s2, 2);
    s += __shfl_xor(s, 4);  s2 += __shfl_xor(s2, 4);
    s += __shfl_xor(s, 8);  s2 += __shfl_xor(s2, 8);
    ps[r] = s;
    ps2[r] = s2;
  }
  if (c == 0) {
#pragma unroll
    for (int r = 0; r < 4; ++r) {
      rsum[(4 * g + r) * 4 + w] = ps[r];
      rsq[(4 * g + r) * 4 + w] = ps2[r];
    }
  }
  __syncthreads();

#pragma unroll
  for (int r = 0; r < 4; ++r) {
    int rl = 4 * g + r;
    float4 sv = *(const float4*)&rsum[rl * 4];
    float4 qv = *(const float4*)&rsq[rl * 4];
    float sum = (sv.x + sv.y) + (sv.z + sv.w);
    float sq  = (qv.x + qv.y) + (qv.z + qv.w);
    float mu = sum * (1.f / 512.f);
    float var = sq * (1.f / 512.f) - mu * mu;
    float rs = rsqrtf(var + 1e-5f);
#pragma unroll
    for (int n = 0; n < 8; ++n) {
      int col = wcol + n * 16 + c;
      out[(size_t)(m0 + rl) * 512 + col] =
          gamma[col] * (acc2[n][r] - mu) * rs + beta[col];
    }
  }
}

extern "C" void kernel_launch(void* const* d_in, const int* in_sizes, int n_in,
                              void* d_out, int out_size, void* d_ws, size_t ws_size,
                              hipStream_t stream) {
  const float* x  = (const float*)d_in[0];
  const float* Wq = (const float*)d_in[1];
  const float* Wk = (const float*)d_in[2];
  const float* Wv = (const float*)d_in[3];
  const float* Wp = (const float*)d_in[4];
  const float* g  = (const float*)d_in[5];
  const float* be = (const float*)d_in[6];
  float* out = (float*)d_out;

  char* ws = (char*)d_ws;
  bf16* xb   = (bf16*)(ws);                          // 8,388,608 B
  bf16* wqkv = (bf16*)(ws + 8388608);                // 1,572,864 B
  bf16* wpb  = (bf16*)(ws + 9961472);                //   524,288 B
  bf16* qkv  = (bf16*)(ws + 10485760);               // 25,165,824 B

  prep_kernel<<<2560, 256, 0, stream>>>(x, Wq, Wk, Wv, Wp, xb, wqkv, wpb);
  // QKV: M=8192 (64 tiles of 128), N=1536 (24 tiles of 64) -> 1536 blocks
  gemm_qkv_kernel<<<1536, 256, 0, stream>>>(xb, wqkv, qkv);
  // fused attn + proj + residual + LN: 8192/16 = 512 blocks (2 blocks/CU)
  attn_proj_ln_kernel<<<512, 256, 0, stream>>>(qkv, wpb, x, g, be, out);
}

// Round 19
// 62.571 us; speedup vs baseline: 1.1343x; 1.1343x over previous
//
#include <hip/hip_runtime.h>
#include <hip/hip_bf16.h>
#include <stdint.h>

typedef __bf16 bf16;
typedef __attribute__((ext_vector_type(8))) __bf16 bf16x8;
typedef __attribute__((ext_vector_type(2))) __bf16 bf16x2;
typedef __attribute__((ext_vector_type(4))) float f32x4;
typedef __attribute__((ext_vector_type(4))) unsigned int u32x4;

#define GLOAD16(gsrc, ldst)                                              \
  __builtin_amdgcn_global_load_lds(                                      \
      (const __attribute__((address_space(1))) unsigned int*)(gsrc),     \
      (__attribute__((address_space(3))) unsigned int*)(ldst), 16, 0, 0)

static constexpr int T_LEN = 4096;
static constexpr int WIN = 16;

__device__ __forceinline__ bf16x8 cvt8(float4 a, float4 b) {
  bf16x8 o;
  o[0] = (bf16)a.x; o[1] = (bf16)a.y; o[2] = (bf16)a.z; o[3] = (bf16)a.w;
  o[4] = (bf16)b.x; o[5] = (bf16)b.y; o[6] = (bf16)b.z; o[7] = (bf16)b.w;
  return o;
}

// ---- fused casts: blocks 0..2047 -> x, 2048..2559 -> weights ----
__global__ __launch_bounds__(256) void prep_kernel(const float* __restrict__ x,
                                                   const float* __restrict__ wq,
                                                   const float* __restrict__ wk,
                                                   const float* __restrict__ wv,
                                                   const float* __restrict__ wp,
                                                   bf16* __restrict__ xb,
                                                   bf16* __restrict__ wqkv,
                                                   bf16* __restrict__ wpb) {
  int bid = blockIdx.x;
  if (bid < 2048) {
    int i = bid * 256 + threadIdx.x;
    const float4* s4 = (const float4*)x + (size_t)i * 2;
    ((bf16x8*)xb)[i] = cvt8(s4[0], s4[1]);
  } else {
    int i = (bid - 2048) * 256 + threadIdx.x;
    int which = i >> 15;
    int j = i & 32767;
    const float* src = (which == 0) ? wq : (which == 1) ? wk : (which == 2) ? wv : wp;
    bf16* dst = (which < 3) ? (wqkv + (size_t)which * 512 * 512) : wpb;
    const float4* s4 = (const float4*)src + (size_t)j * 2;
    ((bf16x8*)dst)[j] = cvt8(s4[0], s4[1]);
  }
}

// ---- QKV GEMM: single-buffer 2-barrier loop, 128x64 tiles -> 1536 blocks ----
__global__ __launch_bounds__(256) void gemm_qkv_kernel(const bf16* __restrict__ Ab,
                                                       const bf16* __restrict__ Bw,
                                                       bf16* __restrict__ Cb) {
  constexpr int K = 512, BK = 64, NIT = K / BK;  // 8
  __shared__ __align__(16) bf16 As[8192];  // 128 rows x 64
  __shared__ __align__(16) bf16 Bs[4096];  // 64 rows x 64
  const int tid = threadIdx.x;
  const int l = tid & 63;
  const int w = tid >> 6;
  const int g = l >> 4;
  const int c = l & 15;
  int bid = blockIdx.x;
  bid = (bid & 7) * 192 + (bid >> 3);  // XCD swizzle (1536 = 8*192)
  const int m0 = (bid / 24) * 128;     // 64 M-tiles
  const int n0 = (bid % 24) * 64;      // 24 N-tiles

  const int wm = (w >> 1) * 64;
  const int wn = (w & 1) * 32;
  const int cx = c & 7;

  const f32x4 zero = {0.f, 0.f, 0.f, 0.f};
  f32x4 acc[4][2];
#pragma unroll
  for (int i = 0; i < 4; ++i)
#pragma unroll
    for (int j = 0; j < 2; ++j) acc[i][j] = zero;

#pragma unroll 1
  for (int t = 0; t < NIT; ++t) {
    const int k0 = t * BK;
#pragma unroll
    for (int i = 0; i < 4; ++i) {  // A: 128 rows x 8 chunks = 1024 slots
      int s = tid + i * 256;
      int row = s >> 3;
      int j = s & 7;
      GLOAD16(Ab + (size_t)(m0 + row) * 512 + k0 + ((j ^ (row & 7)) << 3),
              &As[s * 8]);
    }
#pragma unroll
    for (int i = 0; i < 2; ++i) {  // B: 64 rows x 8 chunks = 512 slots
      int s = tid + i * 256;
      int row = s >> 3;
      int j = s & 7;
      GLOAD16(Bw + (size_t)(n0 + row) * 512 + k0 + ((j ^ (row & 7)) << 3),
              &Bs[s * 8]);
    }
    __syncthreads();
#pragma unroll
    for (int kk = 0; kk < 2; ++kk) {
      const int joff = ((kk * 4 + g) ^ cx) << 3;
      bf16x8 af[4], bfr[2];
#pragma unroll
      for (int mi = 0; mi < 4; ++mi)
        af[mi] = *(const bf16x8*)&As[(wm + mi * 16 + c) * 64 + joff];
#pragma unroll
      for (int ni = 0; ni < 2; ++ni)
        bfr[ni] = *(const bf16x8*)&Bs[(wn + ni * 16 + c) * 64 + joff];
#pragma unroll
      for (int mi = 0; mi < 4; ++mi)
#pragma unroll
        for (int ni = 0; ni < 2; ++ni)
          acc[mi][ni] = __builtin_amdgcn_mfma_f32_16x16x32_bf16(af[mi], bfr[ni], acc[mi][ni], 0, 0, 0);
    }
    __syncthreads();
  }

  // ---- C epilogue: wave-private LDS bounce (64x32, 4KB/wave in As) ----
  bf16* Cw = &As[w * 2048];
  const int r0 = (l >> 4) * 4;
#pragma unroll
  for (int mi = 0; mi < 4; ++mi)
#pragma unroll
    for (int ni = 0; ni < 2; ++ni)
#pragma unroll
      for (int r = 0; r < 4; ++r)
        Cw[(mi * 16 + r0 + r) * 32 + ni * 16 + c] = (bf16)acc[mi][ni][r];
#pragma unroll
  for (int i = 0; i < 4; ++i) {
    int row = (l >> 2) + 16 * i;
    bf16x8 v = *(const bf16x8*)&Cw[row * 32 + (l & 3) * 8];
    *(bf16x8*)(Cb + (size_t)(m0 + wm + row) * 1536 + n0 + wn + (l & 3) * 8) = v;
  }
}

// ---- standalone local attention (VERBATIM R10/R11-verified; ~2 us) ----
static constexpr int TCB = 64;
static constexpr int NP = 96;
static constexpr int KST = 72;
static constexpr int NPT = 112;  // Vt col count (96 window + 16 zero halo)

__global__ __launch_bounds__(256) void attn_kernel(const bf16* __restrict__ qkv,
                                                   bf16* __restrict__ aout) {
  __shared__ __align__(16) bf16 Kl[NP * KST];
  __shared__ __align__(16) unsigned short Vt[64 * NPT];  // V^T[d][p]
  __shared__ __align__(16) bf16 QPO[4 * 16 * 72];

  const int tid = threadIdx.x;
  const int wid = tid >> 6;
  const int l = tid & 63;
  const int g = l >> 4;
  const int c = l & 15;

  const int bid = blockIdx.x;  // 1024 = 2 * 8 * 64
  const int chunk = bid & 63;
  const int h = (bid >> 6) & 7;
  const int b = bid >> 9;
  const int t0 = chunk * TCB;
  const int base = b * T_LEN;

  // ---- stage K row-major, V transposed ----
#pragma unroll
  for (int i = 0; i < 3; ++i) {
    int task = tid + i * 256;  // 768 = 96 pos x 8 col-chunks
    int p = task >> 3;
    int c8 = (task & 7) * 8;
    int pg = min(max(t0 - WIN + p, 0), T_LEN - 1);
    const bf16* kr = qkv + (size_t)(base + pg) * 1536 + 512 + h * 64 + c8;
    const bf16* vr = qkv + (size_t)(base + pg) * 1536 + 1024 + h * 64 + c8;
    *(bf16x8*)&Kl[p * KST + c8] = *(const bf16x8*)kr;
    bf16x8 vv = *(const bf16x8*)vr;
#pragma unroll
    for (int e = 0; e < 8; ++e)
      Vt[(c8 + e) * NPT + p] = ((const unsigned short*)&vv)[e];
  }
  // ---- stage Q (coalesced) into per-wave overlay regions ----
#pragma unroll
  for (int i = 0; i < 2; ++i) {
    int task = tid + i * 256;  // 512 = 64 rows x 8 chunks
    int p = task >> 3;
    int c8 = (task & 7) * 8;
    const bf16* qr = qkv + (size_t)(base + t0 + p) * 1536 + h * 64 + c8;
    *(bf16x8*)&QPO[(p >> 4) * 1152 + (p & 15) * 72 + c8] = *(const bf16x8*)qr;
  }
  // zero-fill Vt halo cols p=96..111 (read where P=0; must be finite)
  {
    int d = tid >> 2;
    int p0 = 96 + (tid & 3) * 4;
    *(uint2*)&Vt[d * NPT + p0] = make_uint2(0u, 0u);
  }
  __syncthreads();

  const int tg = t0 + wid * 16;
  const float scale = 0.125f;

  bf16* Qw = &QPO[wid * 1152];
  bf16x8 qf0 = *(const bf16x8*)&Qw[c * 72 + g * 8];
  bf16x8 qf1 = *(const bf16x8*)&Qw[c * 72 + 32 + g * 8];

  const f32x4 zero = {0.f, 0.f, 0.f, 0.f};
  const u32x4 zu = {0u, 0u, 0u, 0u};

  f32x4 st[3];
#pragma unroll
  for (int wt = 0; wt < 3; ++wt) {
    int rk = 16 * wid + 16 * wt + c;
    bf16x8 ka0 = *(const bf16x8*)&Kl[rk * KST + g * 8];
    bf16x8 ka1 = *(const bf16x8*)&Kl[rk * KST + 32 + g * 8];
    f32x4 t = __builtin_amdgcn_mfma_f32_16x16x32_bf16(ka0, qf0, zero, 0, 0, 0);
    st[wt] = __builtin_amdgcn_mfma_f32_16x16x32_bf16(ka1, qf1, t, 0, 0, 0);
  }

  float pv[3][4];
  float lsum = 0.f;
#pragma unroll
  for (int wt = 0; wt < 3; ++wt)
#pragma unroll
    for (int r = 0; r < 4; ++r) {
      int w = 16 * wt + 4 * g + r;
      int pos = tg - WIN + w;
      bool valid = (w >= c) && (w <= c + 32) && (pos >= 0) && (pos < T_LEN);
      float e = __expf(st[wt][r] * scale);
      pv[wt][r] = valid ? e : 0.f;
      lsum += pv[wt][r];
    }
  lsum += __shfl_xor(lsum, 16);
  lsum += __shfl_xor(lsum, 32);
  float inv = 1.f / lsum;

  bf16* P = Qw;
#pragma unroll
  for (int wt = 0; wt < 3; ++wt) {
    bf16x2 p01, p23;
    p01[0] = (bf16)(pv[wt][0] * inv);
    p01[1] = (bf16)(pv[wt][1] * inv);
    p23[0] = (bf16)(pv[wt][2] * inv);
    p23[1] = (bf16)(pv[wt][3] * inv);
    *(bf16x2*)&P[c * 56 + 16 * wt + 4 * g]     = p01;
    *(bf16x2*)&P[c * 56 + 16 * wt + 4 * g + 2] = p23;
  }

  bf16x8 pa0 = *(const bf16x8*)&P[c * 56 + 8 * g];
  int g1 = (g < 2) ? g : 1;
  bf16x8 pa1 = *(const bf16x8*)&P[c * 56 + 32 + 8 * g1];
  if (g >= 2) pa1 = __builtin_bit_cast(bf16x8, zu);

  f32x4 acc[4] = {zero, zero, zero, zero};
#pragma unroll
  for (int dt = 0; dt < 4; ++dt) {
    const unsigned short* vp = &Vt[(16 * dt + c) * NPT + 16 * wid + 8 * g];
    bf16x8 v0 = *(const bf16x8*)(vp);
    bf16x8 v1 = *(const bf16x8*)(vp + 32);
    acc[dt] = __builtin_amdgcn_mfma_f32_16x16x32_bf16(pa0, v0, acc[dt], 0, 0, 0);
    acc[dt] = __builtin_amdgcn_mfma_f32_16x16x32_bf16(pa1, v1, acc[dt], 0, 0, 0);
  }

  bf16* O = Qw;
#pragma unroll
  for (int dt = 0; dt < 4; ++dt)
#pragma unroll
    for (int r = 0; r < 4; ++r)
      O[(4 * g + r) * 72 + 16 * dt + c] = (bf16)acc[dt][r];

  bf16x8 o0 = *(const bf16x8*)&O[c * 72 + g * 8];
  bf16x8 o1 = *(const bf16x8*)&O[c * 72 + 32 + g * 8];
  bf16* orow = aout + (size_t)(base + tg + c) * 512 + h * 64;
  *(bf16x8*)(orow + g * 8) = o0;
  *(bf16x8*)(orow + 32 + g * 8) = o1;
}

// ---- proj GEMM + residual + LN: BK=32 -> LDS 36.8KB -> 4 blocks/CU ----
__global__ __launch_bounds__(512) void proj_ln_kernel(const bf16* __restrict__ A,
                                                      const bf16* __restrict__ Bw,
                                                      const float* __restrict__ X,
                                                      const float* __restrict__ gamma,
                                                      const float* __restrict__ beta,
                                                      float* __restrict__ out) {
  constexpr int K = 512, BK = 32, BM = 32, NIT = K / BK;  // 16
  __shared__ __align__(16) bf16 As[BM * BK];    // 2 KB
  __shared__ __align__(16) bf16 Bs[512 * BK];   // 32 KB
  __shared__ __align__(16) float rsum[32][8];
  __shared__ __align__(16) float rsq[32][8];

  const int tid = threadIdx.x;
  const int w = tid >> 6;
  const int l = tid & 63;
  const int g = l >> 4;
  const int c = l & 15;
  int bid = blockIdx.x;
  bid = (bid & 7) * 32 + (bid >> 3);  // XCD swizzle: 256 = 8*32
  const int m0 = bid * BM;

  const f32x4 zero = {0.f, 0.f, 0.f, 0.f};
  f32x4 acc[2][4];
#pragma unroll
  for (int m = 0; m < 2; ++m)
#pragma unroll
    for (int n = 0; n < 4; ++n) acc[m][n] = zero;

  const int joff = ((g ^ (c & 3)) << 3);  // k-map k = 8g+e; XOR key row&3

#pragma unroll 1
  for (int t = 0; t < NIT; ++t) {
    const int k0 = t * BK;
    if (tid < 128) {  // A: 32 rows x 4 chunks = 128 slots
      int row = tid >> 2;
      int j = tid & 3;
      GLOAD16(A + (size_t)(m0 + row) * 512 + k0 + ((j ^ (row & 3)) << 3),
              &As[tid * 8]);
    }
#pragma unroll
    for (int i = 0; i < 4; ++i) {  // B: 512 rows x 4 chunks = 2048 slots
      int s = tid + i * 512;
      int row = s >> 2;
      int j = s & 3;
      GLOAD16(Bw + (size_t)row * 512 + k0 + ((j ^ (row & 3)) << 3), &Bs[s * 8]);
    }
    __syncthreads();
    bf16x8 af[2], bfv[4];
#pragma unroll
    for (int m = 0; m < 2; ++m)
      af[m] = *(const bf16x8*)&As[(m * 16 + c) * BK + joff];
#pragma unroll
    for (int n = 0; n < 4; ++n)
      bfv[n] = *(const bf16x8*)&Bs[(w * 64 + n * 16 + c) * BK + joff];
#pragma unroll
    for (int m = 0; m < 2; ++m)
#pragma unroll
      for (int n = 0; n < 4; ++n)
        acc[m][n] = __builtin_amdgcn_mfma_f32_16x16x32_bf16(af[m], bfv[n], acc[m][n], 0, 0, 0);
    __syncthreads();
  }

  const int col0 = w * 64 + c;
  float ps[2][4], ps2[2][4];
#pragma unroll
  for (int m = 0; m < 2; ++m)
#pragma unroll
    for (int r = 0; r < 4; ++r) {
      int row = m0 + m * 16 + 4 * g + r;
      float s = 0.f, s2 = 0.f;
#pragma unroll
      for (int n = 0; n < 4; ++n) {
        float y = acc[m][n][r] + X[(size_t)row * 512 + col0 + n * 16];
        acc[m][n][r] = y;
        s += y;
        s2 += y * y;
      }
      ps[m][r] = s;
      ps2[m][r] = s2;
    }
#pragma unroll
  for (int m = 0; m < 2; ++m)
#pragma unroll
    for (int r = 0; r < 4; ++r) {
      float s = ps[m][r], s2 = ps2[m][r];
      s += __shfl_xor(s, 1);  s2 += __shfl_xor(s2, 1);
      s += __shfl_xor(s, 2);  s2 += __shfl_xor(s2, 2);
      s += __shfl_xor(s, 4);  s2 += __shfl_xor(s2, 4);
      s += __shfl_xor(s, 8);  s2 += __shfl_xor(s2, 8);
      ps[m][r] = s;
      ps2[m][r] = s2;
    }
  if (c == 0) {
#pragma unroll
    for (int m = 0; m < 2; ++m)
#pragma unroll
      for (int r = 0; r < 4; ++r) {
        rsum[m * 16 + 4 * g + r][w] = ps[m][r];
        rsq[m * 16 + 4 * g + r][w] = ps2[m][r];
      }
  }
  __syncthreads();

  float gam[4], bet[4];
#pragma unroll
  for (int n = 0; n < 4; ++n) {
    gam[n] = gamma[col0 + n * 16];
    bet[n] = beta[col0 + n * 16];
  }
#pragma unroll
  for (int m = 0; m < 2; ++m)
#pragma unroll
    for (int r = 0; r < 4; ++r) {
      int rl = m * 16 + 4 * g + r;
      float4 s0 = *(const float4*)&rsum[rl][0];
      float4 s1 = *(const float4*)&rsum[rl][4];
      float4 q0 = *(const float4*)&rsq[rl][0];
      float4 q1 = *(const float4*)&rsq[rl][4];
      float sum = (s0.x + s0.y + s0.z + s0.w) + (s1.x + s1.y + s1.z + s1.w);
      float sq  = (q0.x + q0.y + q0.z + q0.w) + (q1.x + q1.y + q1.z + q1.w);
      float mu = sum * (1.f / 512.f);
      float var = sq * (1.f / 512.f) - mu * mu;
      float rs = rsqrtf(var + 1e-5f);
#pragma unroll
      for (int n = 0; n < 4; ++n)
        out[(size_t)(m0 + rl) * 512 + col0 + n * 16] =
            gam[n] * (acc[m][n][r] - mu) * rs + bet[n];
    }
}

extern "C" void kernel_launch(void* const* d_in, const int* in_sizes, int n_in,
                              void* d_out, int out_size, void* d_ws, size_t ws_size,
                              hipStream_t stream) {
  const float* x  = (const float*)d_in[0];
  const float* Wq = (const float*)d_in[1];
  const float* Wk = (const float*)d_in[2];
  const float* Wv = (const float*)d_in[3];
  const float* Wp = (const float*)d_in[4];
  const float* g  = (const float*)d_in[5];
  const float* be = (const float*)d_in[6];
  float* out = (float*)d_out;

  char* ws = (char*)d_ws;
  bf16* xb   = (bf16*)(ws);                          // 8,388,608 B
  bf16* wqkv = (bf16*)(ws + 8388608);                // 1,572,864 B
  bf16* wpb  = (bf16*)(ws + 9961472);                //   524,288 B
  bf16* qkv  = (bf16*)(ws + 10485760);               // 25,165,824 B
  bf16* aout = (bf16*)(ws + 35651584);               // 8,388,608 B

  prep_kernel<<<2560, 256, 0, stream>>>(x, Wq, Wk, Wv, Wp, xb, wqkv, wpb);
  // QKV: M=8192 (64 tiles of 128), N=1536 (24 tiles of 64) -> 1536 blocks
  gemm_qkv_kernel<<<1536, 256, 0, stream>>>(xb, wqkv, qkv);
  // attn: blocks = B(2) * H(8) * T/TCB(64) = 1024  (~2 us measured)
  attn_kernel<<<1024, 256, 0, stream>>>(qkv, aout);
  // proj + residual + LN: 256 blocks, 4 blocks/CU
  proj_ln_kernel<<<256, 512, 0, stream>>>(aout, wpb, x, g, be, out);
}

// Round 20
// 57.359 us; speedup vs baseline: 1.2374x; 1.0909x over previous
//
#include <hip/hip_runtime.h>
#include <hip/hip_bf16.h>
#include <stdint.h>

typedef __bf16 bf16;
typedef __attribute__((ext_vector_type(8))) __bf16 bf16x8;
typedef __attribute__((ext_vector_type(2))) __bf16 bf16x2;
typedef __attribute__((ext_vector_type(4))) float f32x4;
typedef __attribute__((ext_vector_type(4))) unsigned int u32x4;

#define GLOAD16(gsrc, ldst)                                              \
  __builtin_amdgcn_global_load_lds(                                      \
      (const __attribute__((address_space(1))) unsigned int*)(gsrc),     \
      (__attribute__((address_space(3))) unsigned int*)(ldst), 16, 0, 0)

static constexpr int T_LEN = 4096;
static constexpr int WIN = 16;

__device__ __forceinline__ bf16x8 cvt8(float4 a, float4 b) {
  bf16x8 o;
  o[0] = (bf16)a.x; o[1] = (bf16)a.y; o[2] = (bf16)a.z; o[3] = (bf16)a.w;
  o[4] = (bf16)b.x; o[5] = (bf16)b.y; o[6] = (bf16)b.z; o[7] = (bf16)b.w;
  return o;
}

// ---- fused casts: blocks 0..2047 -> x, 2048..2559 -> weights ----
__global__ __launch_bounds__(256) void prep_kernel(const float* __restrict__ x,
                                                   const float* __restrict__ wq,
                                                   const float* __restrict__ wk,
                                                   const float* __restrict__ wv,
                                                   const float* __restrict__ wp,
                                                   bf16* __restrict__ xb,
                                                   bf16* __restrict__ wqkv,
                                                   bf16* __restrict__ wpb) {
  int bid = blockIdx.x;
  if (bid < 2048) {
    int i = bid * 256 + threadIdx.x;
    const float4* s4 = (const float4*)x + (size_t)i * 2;
    ((bf16x8*)xb)[i] = cvt8(s4[0], s4[1]);
  } else {
    int i = (bid - 2048) * 256 + threadIdx.x;
    int which = i >> 15;
    int j = i & 32767;
    const float* src = (which == 0) ? wq : (which == 1) ? wk : (which == 2) ? wv : wp;
    bf16* dst = (which < 3) ? (wqkv + (size_t)which * 512 * 512) : wpb;
    const float4* s4 = (const float4*)src + (size_t)j * 2;
    ((bf16x8*)dst)[j] = cvt8(s4[0], s4[1]);
  }
}

// ---- QKV GEMM: single-buffer 2-barrier loop, 128x64 tiles -> 1536 blocks ----
__global__ __launch_bounds__(256) void gemm_qkv_kernel(const bf16* __restrict__ Ab,
                                                       const bf16* __restrict__ Bw,
                                                       bf16* __restrict__ Cb) {
  constexpr int K = 512, BK = 64, NIT = K / BK;  // 8
  __shared__ __align__(16) bf16 As[8192];  // 128 rows x 64
  __shared__ __align__(16) bf16 Bs[4096];  // 64 rows x 64
  const int tid = threadIdx.x;
  const int l = tid & 63;
  const int w = tid >> 6;
  const int g = l >> 4;
  const int c = l & 15;
  int bid = blockIdx.x;
  bid = (bid & 7) * 192 + (bid >> 3);  // XCD swizzle (1536 = 8*192)
  const int m0 = (bid / 24) * 128;     // 64 M-tiles
  const int n0 = (bid % 24) * 64;      // 24 N-tiles

  const int wm = (w >> 1) * 64;
  const int wn = (w & 1) * 32;
  const int cx = c & 7;

  const f32x4 zero = {0.f, 0.f, 0.f, 0.f};
  f32x4 acc[4][2];
#pragma unroll
  for (int i = 0; i < 4; ++i)
#pragma unroll
    for (int j = 0; j < 2; ++j) acc[i][j] = zero;

#pragma unroll 1
  for (int t = 0; t < NIT; ++t) {
    const int k0 = t * BK;
#pragma unroll
    for (int i = 0; i < 4; ++i) {  // A: 128 rows x 8 chunks = 1024 slots
      int s = tid + i * 256;
      int row = s >> 3;
      int j = s & 7;
      GLOAD16(Ab + (size_t)(m0 + row) * 512 + k0 + ((j ^ (row & 7)) << 3),
              &As[s * 8]);
    }
#pragma unroll
    for (int i = 0; i < 2; ++i) {  // B: 64 rows x 8 chunks = 512 slots
      int s = tid + i * 256;
      int row = s >> 3;
      int j = s & 7;
      GLOAD16(Bw + (size_t)(n0 + row) * 512 + k0 + ((j ^ (row & 7)) << 3),
              &Bs[s * 8]);
    }
    __syncthreads();
#pragma unroll
    for (int kk = 0; kk < 2; ++kk) {
      const int joff = ((kk * 4 + g) ^ cx) << 3;
      bf16x8 af[4], bfr[2];
#pragma unroll
      for (int mi = 0; mi < 4; ++mi)
        af[mi] = *(const bf16x8*)&As[(wm + mi * 16 + c) * 64 + joff];
#pragma unroll
      for (int ni = 0; ni < 2; ++ni)
        bfr[ni] = *(const bf16x8*)&Bs[(wn + ni * 16 + c) * 64 + joff];
#pragma unroll
      for (int mi = 0; mi < 4; ++mi)
#pragma unroll
        for (int ni = 0; ni < 2; ++ni)
          acc[mi][ni] = __builtin_amdgcn_mfma_f32_16x16x32_bf16(af[mi], bfr[ni], acc[mi][ni], 0, 0, 0);
    }
    __syncthreads();
  }

  // ---- C epilogue: wave-private LDS bounce (64x32, 4KB/wave in As) ----
  bf16* Cw = &As[w * 2048];
  const int r0 = (l >> 4) * 4;
#pragma unroll
  for (int mi = 0; mi < 4; ++mi)
#pragma unroll
    for (int ni = 0; ni < 2; ++ni)
#pragma unroll
      for (int r = 0; r < 4; ++r)
        Cw[(mi * 16 + r0 + r) * 32 + ni * 16 + c] = (bf16)acc[mi][ni][r];
#pragma unroll
  for (int i = 0; i < 4; ++i) {
    int row = (l >> 2) + 16 * i;
    bf16x8 v = *(const bf16x8*)&Cw[row * 32 + (l & 3) * 8];
    *(bf16x8*)(Cb + (size_t)(m0 + wm + row) * 1536 + n0 + wn + (l & 3) * 8) = v;
  }
}

// ---- FUSED attn + proj + residual + LayerNorm (R17-verified) ----
// Only change vs R17: rotated V^T scatter (er = (e + c8/8) & 7) -> staging
// ds_writes hit banks {b, b+4, ..., b+28} instead of one bank (8-way -> ~2-way).
__global__ __launch_bounds__(512) void attn_proj_ln_kernel(
    const bf16* __restrict__ qkv, const bf16* __restrict__ Bw,
    const float* __restrict__ X, const float* __restrict__ gamma,
    const float* __restrict__ beta, float* __restrict__ out) {
  __shared__ __align__(16) bf16 POOL[63744];  // 127,488 B
  bf16* KV = POOL;
  bf16* Pp = POOL + 36864;
  bf16* aoutL = POOL + 46080;
  float* rsum = (float*)(POOL + 62720);
  float* rsq  = (float*)(POOL + 63232);

  const int tid = threadIdx.x;
  const int w = tid >> 6;
  const int l = tid & 63;
  const int g = l >> 4;
  const int c = l & 15;
  const int cx = c & 7;
  int bid = blockIdx.x;
  bid = (bid & 7) * 32 + (bid >> 3);  // XCD swizzle: 256 = 8*32
  const int m0 = bid * 32;
  const int b = m0 >> 12;
  const int tloc0 = m0 & (T_LEN - 1);
  const int base = b * T_LEN;

  const f32x4 zero = {0.f, 0.f, 0.f, 0.f};
  const u32x4 zu = {0u, 0u, 0u, 0u};
  const float scale = 0.125f;

  // ---- one-time zero of Vt pad cols 64..71 for all 4 head-slots x 64 rows ----
  if (tid < 256) {
    int hl = tid >> 6;
    int row = tid & 63;
    *(uint4*)&KV[18432 + hl * 4608 + row * 72 + 64] = make_uint4(0u, 0u, 0u, 0u);
  }

  // ================= attention phase =================
#pragma unroll 1
  for (int pass = 0; pass < 2; ++pass) {
    if (pass) __syncthreads();
#pragma unroll
    for (int i = 0; i < 4; ++i) {
      int task = tid + i * 512;
      int hl = task >> 9;
      int rem = task & 511;
      int pp = rem >> 3;
      int c8 = (rem & 7) * 8;
      int h = pass * 4 + hl;
      int pg = base + min(max(tloc0 - WIN + pp, 0), T_LEN - 1);
      const bf16* kr = qkv + (size_t)pg * 1536 + 512 + h * 64 + c8;
      const bf16* vr = qkv + (size_t)pg * 1536 + 1024 + h * 64 + c8;
      *(bf16x8*)&KV[hl * 4608 + pp * 72 + c8] = *(const bf16x8*)kr;
      bf16x8 vv = *(const bf16x8*)vr;
      bf16* vt = &KV[18432 + hl * 4608];
      int rot = c8 >> 3;
#pragma unroll
      for (int e = 0; e < 8; ++e) {
        int er = (e + rot) & 7;  // rotated scatter -> banks step 4, ~2-way
        vt[(c8 + er) * 72 + pp] = vv[er];
      }
    }
    __syncthreads();

    const int hl = w >> 1;
    const int wh = w & 1;
    const int h = pass * 4 + hl;
    const int tg = tloc0 + wh * 16;
    bf16* Kl = &KV[hl * 4608];
    bf16* Vt = &KV[18432 + hl * 4608];

    const bf16* qrow = qkv + (size_t)(base + tg + c) * 1536 + h * 64;
    bf16x8 qf0 = *(const bf16x8*)(qrow + g * 8);
    bf16x8 qf1 = *(const bf16x8*)(qrow + 32 + g * 8);

    f32x4 st[3];
#pragma unroll
    for (int wt = 0; wt < 3; ++wt) {
      int rk = 16 * wh + 16 * wt + c;
      bf16x8 ka0 = *(const bf16x8*)&Kl[rk * 72 + g * 8];
      bf16x8 ka1 = *(const bf16x8*)&Kl[rk * 72 + 32 + g * 8];
      f32x4 t = __builtin_amdgcn_mfma_f32_16x16x32_bf16(ka0, qf0, zero, 0, 0, 0);
      st[wt] = __builtin_amdgcn_mfma_f32_16x16x32_bf16(ka1, qf1, t, 0, 0, 0);
    }

    float pv[3][4];
    float lsum = 0.f;
#pragma unroll
    for (int wt = 0; wt < 3; ++wt)
#pragma unroll
      for (int r = 0; r < 4; ++r) {
        int ww = 16 * wt + 4 * g + r;
        int pos = tg - WIN + ww;
        bool valid = (ww >= c) && (ww <= c + 32) && (pos >= 0) && (pos < T_LEN);
        float e = __expf(st[wt][r] * scale);
        pv[wt][r] = valid ? e : 0.f;
        lsum += pv[wt][r];
      }
    lsum += __shfl_xor(lsum, 16);
    lsum += __shfl_xor(lsum, 32);
    float inv = 1.f / lsum;

    bf16* P = &Pp[w * 1152];
#pragma unroll
    for (int wt = 0; wt < 3; ++wt) {
      bf16x2 p01, p23;
      p01[0] = (bf16)(pv[wt][0] * inv);
      p01[1] = (bf16)(pv[wt][1] * inv);
      p23[0] = (bf16)(pv[wt][2] * inv);
      p23[1] = (bf16)(pv[wt][3] * inv);
      *(bf16x2*)&P[c * 56 + 16 * wt + 4 * g]     = p01;
      *(bf16x2*)&P[c * 56 + 16 * wt + 4 * g + 2] = p23;
    }

    bf16x8 pa0 = *(const bf16x8*)&P[c * 56 + 8 * g];
    int g1 = (g < 2) ? g : 1;
    bf16x8 pa1 = *(const bf16x8*)&P[c * 56 + 32 + 8 * g1];
    if (g >= 2) pa1 = __builtin_bit_cast(bf16x8, zu);

    const int off0 = 16 * wh + 8 * g;
    const int off1 = 16 * wh + ((g < 2) ? 32 + 8 * g : 48);
    f32x4 acc[4] = {zero, zero, zero, zero};
#pragma unroll
    for (int dt = 0; dt < 4; ++dt) {
      bf16x8 v0 = *(const bf16x8*)&Vt[(16 * dt + c) * 72 + off0];
      bf16x8 v1 = *(const bf16x8*)&Vt[(16 * dt + c) * 72 + off1];
      acc[dt] = __builtin_amdgcn_mfma_f32_16x16x32_bf16(pa0, v0, acc[dt], 0, 0, 0);
      acc[dt] = __builtin_amdgcn_mfma_f32_16x16x32_bf16(pa1, v1, acc[dt], 0, 0, 0);
    }

#pragma unroll
    for (int dt = 0; dt < 4; ++dt)
#pragma unroll
      for (int r = 0; r < 4; ++r)
        aoutL[(wh * 16 + 4 * g + r) * 520 + h * 64 + 16 * dt + c] = (bf16)acc[dt][r];
  }

  // ---- issue proj tile-0 B loads to REGS (overlaps attn tail + barrier) ----
  bf16x8 breg[8];
#pragma unroll
  for (int i = 0; i < 8; ++i) {
    int s = tid + i * 512;
    int row = s >> 3;
    int j = s & 7;
    breg[i] = *(const bf16x8*)(Bw + (size_t)row * 512 + ((j ^ (row & 7)) << 3));
  }
  __syncthreads();  // aout complete; KV region free for B staging

  // ================= proj + residual + LN phase =================
  f32x4 acc2[2][4];
#pragma unroll
  for (int m = 0; m < 2; ++m)
#pragma unroll
    for (int n = 0; n < 4; ++n) acc2[m][n] = zero;

#pragma unroll 1
  for (int t = 0; t < 8; ++t) {
    const int k0 = t * 64;
#pragma unroll
    for (int i = 0; i < 8; ++i) {
      int s = tid + i * 512;
      *(bf16x8*)&KV[s * 8] = breg[i];
    }
    __syncthreads();  // tile t visible to all waves
    if (t < 7) {
      const int k1 = k0 + 64;
#pragma unroll
      for (int i = 0; i < 8; ++i) {
        int s = tid + i * 512;
        int row = s >> 3;
        int j = s & 7;
        breg[i] = *(const bf16x8*)(Bw + (size_t)row * 512 + k1 + ((j ^ (row & 7)) << 3));
      }
    }
#pragma unroll
    for (int kk = 0; kk < 2; ++kk) {
      const int joff = ((kk * 4 + g) ^ cx) << 3;
      bf16x8 af[2], bfv[4];
#pragma unroll
      for (int m = 0; m < 2; ++m)
        af[m] = *(const bf16x8*)&aoutL[(m * 16 + c) * 520 + k0 + (kk * 4 + g) * 8];
#pragma unroll
      for (int n = 0; n < 4; ++n)
        bfv[n] = *(const bf16x8*)&KV[(w * 64 + n * 16 + c) * 64 + joff];
#pragma unroll
      for (int m = 0; m < 2; ++m)
#pragma unroll
        for (int n = 0; n < 4; ++n)
          acc2[m][n] = __builtin_amdgcn_mfma_f32_16x16x32_bf16(af[m], bfv[n], acc2[m][n], 0, 0, 0);
    }
    __syncthreads();  // all reads of tile t done before next ds_write
  }

  const int col0 = w * 64 + c;
  float ps[2][4], ps2[2][4];
#pragma unroll
  for (int m = 0; m < 2; ++m)
#pragma unroll
    for (int r = 0; r < 4; ++r) {
      int row = m0 + m * 16 + 4 * g + r;
      float s = 0.f, s2 = 0.f;
#pragma unroll
      for (int n = 0; n < 4; ++n) {
        float y = acc2[m][n][r] + X[(size_t)row * 512 + col0 + n * 16];
        acc2[m][n][r] = y;
        s += y;
        s2 += y * y;
      }
      ps[m][r] = s;
      ps2[m][r] = s2;
    }
#pragma unroll
  for (int m = 0; m < 2; ++m)
#pragma unroll
    for (int r = 0; r < 4; ++r) {
      float s = ps[m][r], s2 = ps2[m][r];
      s += __shfl_xor(s, 1);  s2 += __shfl_xor(s2, 1);
      s += __shfl_xor(s, 2);  s2 += __shfl_xor(s2, 2);
      s += __shfl_xor(s, 4);  s2 += __shfl_xor(s2, 4);
      s += __shfl_xor(s, 8);  s2 += __shfl_xor(s2, 8);
      ps[m][r] = s;
      ps2[m][r] = s2;
    }
  if (c == 0) {
#pragma unroll
    for (int m = 0; m < 2; ++m)
#pragma unroll
      for (int r = 0; r < 4; ++r) {
        rsum[(m * 16 + 4 * g + r) * 8 + w] = ps[m][r];
        rsq[(m * 16 + 4 * g + r) * 8 + w] = ps2[m][r];
      }
  }
  __syncthreads();

  float gam[4], bet[4];
#pragma unroll
  for (int n = 0; n < 4; ++n) {
    gam[n] = gamma[col0 + n * 16];
    bet[n] = beta[col0 + n * 16];
  }
#pragma unroll
  for (int m = 0; m < 2; ++m)
#pragma unroll
    for (int r = 0; r < 4; ++r) {
      int rl = m * 16 + 4 * g + r;
      float sum = 0.f, sq = 0.f;
#pragma unroll
      for (int j = 0; j < 8; ++j) {
        sum += rsum[rl * 8 + j];
        sq += rsq[rl * 8 + j];
      }
      float mu = sum * (1.f / 512.f);
      float var = sq * (1.f / 512.f) - mu * mu;
      float rs = rsqrtf(var + 1e-5f);
#pragma unroll
      for (int n = 0; n < 4; ++n)
        out[(size_t)(m0 + rl) * 512 + col0 + n * 16] =
            gam[n] * (acc2[m][n][r] - mu) * rs + bet[n];
    }
}

extern "C" void kernel_launch(void* const* d_in, const int* in_sizes, int n_in,
                              void* d_out, int out_size, void* d_ws, size_t ws_size,
                              hipStream_t stream) {
  const float* x  = (const float*)d_in[0];
  const float* Wq = (const float*)d_in[1];
  const float* Wk = (const float*)d_in[2];
  const float* Wv = (const float*)d_in[3];
  const float* Wp = (const float*)d_in[4];
  const float* g  = (const float*)d_in[5];
  const float* be = (const float*)d_in[6];
  float* out = (float*)d_out;

  char* ws = (char*)d_ws;
  bf16* xb   = (bf16*)(ws);                          // 8,388,608 B
  bf16* wqkv = (bf16*)(ws + 8388608);                // 1,572,864 B
  bf16* wpb  = (bf16*)(ws + 9961472);                //   524,288 B
  bf16* qkv  = (bf16*)(ws + 10485760);               // 25,165,824 B

  prep_kernel<<<2560, 256, 0, stream>>>(x, Wq, Wk, Wv, Wp, xb, wqkv, wpb);
  // QKV: M=8192 (64 tiles of 128), N=1536 (24 tiles of 64) -> 1536 blocks
  gemm_qkv_kernel<<<1536, 256, 0, stream>>>(xb, wqkv, qkv);
  // fused attn + proj + residual + LN: 8192/32 = 256 blocks
  attn_proj_ln_kernel<<<256, 512, 0, stream>>>(qkv, wpb, x, g, be, out);
}